// Round 12
// baseline (2403.498 us; speedup 1.0000x reference)
//
#include <hip/hip_runtime.h>

constexpr int NN = 50000;
constexpr int EE = 800000;
constexpr int HH = 128;

typedef __attribute__((ext_vector_type(8))) __bf16 bfv8;
typedef __attribute__((ext_vector_type(4))) float f32x4;
typedef unsigned short u16;

__device__ __forceinline__ u16 f2bf(float x){
  unsigned u = __builtin_bit_cast(unsigned, x);
  u = u + 0x7fffu + ((u >> 16) & 1u);
  return (u16)(u >> 16);
}
// fast silu: v_rcp instead of precise-div sequence (no fast-math in harness)
__device__ __forceinline__ float fsilu(float x){
  return x * __builtin_amdgcn_rcpf(1.f + __expf(-x));
}

// A from wave-private LDS scratch (16 rows x 256B, XOR swizzle (row&7)<<4),
// B via generic pointer: LDS stage -> ds_read_b128, global -> global_load_dwordx4
// (address space inferred after inlining; both variants proven in R7/R11).
template<int KSTEPS, int CB>
__device__ __forceinline__ void mmW(const u16* Arows, const u16* Bp,
                                    const float* __restrict__ bias, int NB, f32x4* acc){
  const int lane = threadIdx.x & 63;
  #pragma unroll
  for (int cb = 0; cb < CB; ++cb){
    int col = cb*16 + (lane & 15);
    float b = (col < NB) ? bias[col] : 0.f;
    acc[cb] = (f32x4){b, b, b, b};
  }
  const int arow = lane & 15;
  const char* abase = (const char*)Arows + arow * 256;
  const int kb = (lane >> 4) * 16;
  const int swz = (arow & 7) << 4;
  const bfv8* bq = (const bfv8*)Bp + lane;
  #pragma unroll
  for (int ks = 0; ks < KSTEPS; ++ks){
    bfv8 a = *(const bfv8*)(abase + ((ks*64 + kb) ^ swz));
    #pragma unroll
    for (int cb = 0; cb < CB; ++cb)
      acc[cb] = __builtin_amdgcn_mfma_f32_16x16x32_bf16(a, bq[(ks*CB + cb) * 64], acc[cb], 0, 0, 0);
  }
}

// silu(acc) -> bf16 into wave scratch (16 rows x 256B, swizzled)
template<int CB>
__device__ __forceinline__ void silu_store(const f32x4* acc, u16* dst){
  const int lane = threadIdx.x & 63;
  #pragma unroll
  for (int cb = 0; cb < CB; ++cb){
    #pragma unroll
    for (int j = 0; j < 4; ++j){
      int row = ((lane >> 4) << 2) + j;
      int col = cb*16 + (lane & 15);
      *(u16*)((char*)dst + row*256 + ((col*2) ^ ((row & 7) << 4))) = f2bf(fsilu(acc[cb][j]));
    }
  }
}

// ---------------- weight packing ----------------
// remap==1 (ew1): packed k order [h(256) | ef(16) | nrm | pad(15)];
// source ew1 rows are [h(256) | nrm@256 | ef@257..272].
struct PackDesc { const float* src; u16* dst; int K; int Nc; int CB; int ksteps; int remap; };
struct PackArgs { PackDesc d[32]; };

__global__ __launch_bounds__(256) void pack_kernel(PackArgs pa){
  PackDesc d = pa.d[blockIdx.x];
  int total = d.ksteps * d.CB * 512;
  for (int p = threadIdx.x; p < total; p += 256){
    int j = p & 7, lane = (p >> 3) & 63, cbk = p >> 9;
    int cb = cbk % d.CB, ks = cbk / d.CB;
    int k = ks*32 + ((lane >> 4) * 8) + j;
    int col = cb*16 + (lane & 15);
    int kk = k;
    if (d.remap && k >= 256) kk = (k < 272) ? (k + 1) : ((k == 272) ? 256 : 0x7fffffff);
    float v = (kk < d.K && col < d.Nc) ? d.src[(size_t)kk * d.Nc + col] : 0.f;
    d.dst[p] = f2bf(v);
  }
}

// ---------------- embedding + coords init ----------------
__global__ __launch_bounds__(256) void embed_kernel(const float* __restrict__ nodes,
    const float* __restrict__ emb_w, const float* __restrict__ emb_b,
    float* __restrict__ hf, u16* __restrict__ hbf, float* __restrict__ coords){
  int t = blockIdx.x * 256 + threadIdx.x;
  int g = t >> 2, q = t & 3;
  if (g >= NN) return;
  const float* x = nodes + (size_t)g * 22;
  float acc[32];
  #pragma unroll
  for (int c = 0; c < 32; ++c) acc[c] = emb_b[q*32 + c];
  for (int k = 0; k < 16; ++k){
    float f = x[6 + k];
    const float* wr = emb_w + k*128 + q*32;
    #pragma unroll
    for (int c = 0; c < 32; ++c) acc[c] += f * wr[c];
  }
  size_t off = (size_t)g * HH + q*32;
  #pragma unroll
  for (int c = 0; c < 32; ++c){ hf[off + c] = acc[c]; hbf[off + c] = f2bf(acc[c]); }
  if (q == 0){
    coords[g*3+0] = x[0]; coords[g*3+1] = x[1]; coords[g*3+2] = x[2];
  }
}

// ---------------- CSR build (once per launch) ----------------
__global__ __launch_bounds__(256) void count_kernel(const int* __restrict__ esrc, int* __restrict__ cnt_i){
  int e = blockIdx.x * 256 + threadIdx.x;
  if (e < EE) atomicAdd(&cnt_i[esrc[e]], 1);
}

__global__ __launch_bounds__(256) void scan_kernel(const int* __restrict__ cnt_i,
    int* __restrict__ row_start, int* __restrict__ fill){
  __shared__ int part[256];
  int t = threadIdx.x;
  int lo = t * 196, hi = lo + 196;
  if (lo > NN) lo = NN;
  if (hi > NN) hi = NN;
  int s = 0;
  for (int i = lo; i < hi; ++i) s += cnt_i[i];
  part[t] = s; __syncthreads();
  for (int d = 1; d < 256; d <<= 1){
    int v = (t >= d) ? part[t-d] : 0;
    __syncthreads();
    part[t] += v;
    __syncthreads();
  }
  int run = part[t] - s;             // exclusive prefix
  for (int i = lo; i < hi; ++i){ row_start[i] = run; fill[i] = run; run += cnt_i[i]; }
  if (t == 255) row_start[NN] = run;
}

__global__ __launch_bounds__(256) void scatter_kernel(const int* __restrict__ esrc,
    const int* __restrict__ edst, int* __restrict__ fill,
    int2* __restrict__ sd_sorted, int* __restrict__ eid_sorted){
  int e = blockIdx.x * 256 + threadIdx.x;
  if (e < EE){
    int s = esrc[e];
    int pos = atomicAdd(&fill[s], 1);
    sd_sorted[pos] = make_int2(s, edst[e]);
    eid_sorted[pos] = e;
  }
}

// ---------------- edge kernel ----------------
// 128 sorted edges/block, 8 waves x 16 rows, ~139KB LDS -> ONE block per CU.
// ew1+ew2 (104KB) staged into LDS once (single barrier); cw1/cw2 stay on the
// global path — with 1 block/CU they are L1-resident (no multi-block thrash,
// the R4..R11 invariant cost). After the one barrier every wave runs a fully
// independent chain (weights read-only, scratch wave-private, Phase-A rows
// wave-own — the R4-proven barrier-free pattern).
__global__ __launch_bounds__(512) void edge_kernel(
    const float* __restrict__ coords, const u16* __restrict__ hbf, const float* __restrict__ ef,
    const int2* __restrict__ sd_sorted, const int* __restrict__ eid_sorted,
    const u16* __restrict__ ew1p, const u16* __restrict__ ew2p,
    const u16* __restrict__ cw1p, const u16* __restrict__ cw2p,
    const float* __restrict__ eb1, const float* __restrict__ eb2,
    const float* __restrict__ cb1, const float* __restrict__ cb2,
    float* __restrict__ agg, float* __restrict__ acc_ct){
  __shared__ __align__(16) u16 sStage[53248];     // ew1 (36864 u16) + ew2 (16384 u16)
  __shared__ __align__(16) u16 sBuf[8][2048];     // 4KB scratch per wave
  __shared__ float4 s_cdn[128];
  __shared__ int s_src[128];
  __shared__ int s_eid[128];

  const int tid = threadIdx.x, wid = tid >> 6, lane = tid & 63;
  const int R = wid * 16;
  const int e0 = blockIdx.x * 128;

  // one-time block-cooperative weight stage (overlaps Phase A)
  {
    const uint4* s1 = (const uint4*)ew1p;
    uint4* d1 = (uint4*)sStage;
    for (int i = tid; i < 4608; i += 512) d1[i] = s1[i];
    const uint4* s2 = (const uint4*)ew2p;
    uint4* d2 = (uint4*)(sStage + 36864);
    for (int i = tid; i < 2048; i += 512) d2[i] = s2[i];
  }

  // Phase A: per-edge scalars (wave-own rows)
  if (lane < 16){
    int row = R + lane;
    int e = e0 + row;
    int2 sd = sd_sorted[e];
    float cx = coords[sd.x*3+0] - coords[sd.y*3+0];
    float cy = coords[sd.x*3+1] - coords[sd.y*3+1];
    float cz = coords[sd.x*3+2] - coords[sd.y*3+2];
    float nrm = sqrtf(cx*cx + cy*cy + cz*cz);
    s_cdn[row] = make_float4(cx, cy, cz, nrm);
    s_src[row] = sd.x; s_eid[row] = eid_sorted[e];
  }
  __syncthreads();                                  // stage ready; only barrier

  const int myrow = R + (lane & 15);
  const int g = lane >> 4;
  int2 sd = sd_sorted[e0 + myrow];                  // L1/L2-hot re-read
  const u16* hsb = hbf + (size_t)sd.x * HH + g*8;
  const u16* hdb = hbf + (size_t)sd.y * HH + g*8;
  u16* sB = sBuf[wid];
  const bfv8* bqs = (const bfv8*)sStage + lane;     // ew1 B in LDS

  f32x4 acc[8];
  // ---- ew1: x @ ew1 + eb1 (A direct from global hbf, B from LDS) ----
  {
    #pragma unroll
    for (int cb = 0; cb < 8; ++cb){
      float b = eb1[cb*16 + (lane & 15)];
      acc[cb] = (f32x4){b, b, b, b};
    }
    #pragma unroll
    for (int ks = 0; ks < 4; ++ks){
      bfv8 a = *(const bfv8*)(hsb + ks*32);
      #pragma unroll
      for (int cb = 0; cb < 8; ++cb)
        acc[cb] = __builtin_amdgcn_mfma_f32_16x16x32_bf16(a, bqs[(ks*8 + cb)*64], acc[cb], 0, 0, 0);
    }
    #pragma unroll
    for (int ks = 4; ks < 8; ++ks){
      bfv8 a = *(const bfv8*)(hdb + (ks - 4)*32);
      #pragma unroll
      for (int cb = 0; cb < 8; ++cb)
        acc[cb] = __builtin_amdgcn_mfma_f32_16x16x32_bf16(a, bqs[(ks*8 + cb)*64], acc[cb], 0, 0, 0);
    }
    // tail ks=8: cols [ef(16) | nrm | pad]; lane-group g holds k 256+g*8..+7
    const int my_eid = s_eid[myrow];
    union { bfv8 v; u16 s[8]; unsigned u[4]; } at;
    at.u[0] = at.u[1] = at.u[2] = at.u[3] = 0u;
    if (g < 2){
      float4 f0 = *(const float4*)(ef + (size_t)my_eid * 16 + g*8);
      float4 f1 = *(const float4*)(ef + (size_t)my_eid * 16 + g*8 + 4);
      at.u[0] = f2bf(f0.x) | ((unsigned)f2bf(f0.y) << 16);
      at.u[1] = f2bf(f0.z) | ((unsigned)f2bf(f0.w) << 16);
      at.u[2] = f2bf(f1.x) | ((unsigned)f2bf(f1.y) << 16);
      at.u[3] = f2bf(f1.z) | ((unsigned)f2bf(f1.w) << 16);
    } else if (g == 2){
      at.s[0] = f2bf(s_cdn[myrow].w);
    }
    #pragma unroll
    for (int cb = 0; cb < 8; ++cb)
      acc[cb] = __builtin_amdgcn_mfma_f32_16x16x32_bf16(at.v, bqs[(8*8 + cb)*64], acc[cb], 0, 0, 0);
  }
  silu_store<8>(acc, sB);                           // w(B), wave-private

  mmW<4, 8>(sB, sStage + 36864, eb2, 128, acc);     // r(B): silu(.) @ ew2 (B in LDS)
  // m: silu, segmented-reduce over sorted rows, flush atomics; bf16 -> sB
  {
    const int rb = (lane >> 4) << 2;
    float run[8];
    #pragma unroll
    for (int cb = 0; cb < 8; ++cb) run[cb] = 0.f;
    #pragma unroll
    for (int j = 0; j < 4; ++j){
      int lrow = rb + j, grow = R + lrow;
      int src = s_src[grow];
      bool flush = (j == 3) || (s_src[grow + 1] != src);
      #pragma unroll
      for (int cb = 0; cb < 8; ++cb){
        int col = cb*16 + (lane & 15);
        float m = fsilu(acc[cb][j]);
        run[cb] += m;
        *(u16*)((char*)sB + lrow*256 + ((col*2) ^ ((lrow & 7) << 4))) = f2bf(m);
      }
      if (flush){
        #pragma unroll
        for (int cb = 0; cb < 8; ++cb){
          int col = cb*16 + (lane & 15);
          atomicAdd(&agg[(size_t)src * HH + col], run[cb]);
          run[cb] = 0.f;
        }
      }
    }
  }

  mmW<4, 8>(sB, cw1p, cb1, 128, acc);               // r(B): m @ cw1 (B global, L1-resident)
  silu_store<8>(acc, sB);

  f32x4 a4[1];
  mmW<4, 1>(sB, cw2p, cb2, 3, a4);                  // r(B): silu(.) @ cw2 (B global)
  {
    int col = lane & 15;
    if (col < 3){
      const int rb = (lane >> 4) << 2;
      float run = 0.f;
      #pragma unroll
      for (int j = 0; j < 4; ++j){
        int grow = R + rb + j;
        float4 cdn = s_cdn[grow];
        float cdv = (col == 0) ? cdn.x : ((col == 1) ? cdn.y : cdn.z);
        run += cdv * a4[0][j];
        int src = s_src[grow];
        if (j == 3 || s_src[grow + 1] != src){
          atomicAdd(&acc_ct[(size_t)src * 3 + col], run);
          run = 0.f;
        }
      }
    }
  }
}

// ---------------- node kernel (unchanged from R11) ----------------
__device__ __forceinline__ void mm_lds1(const u16* Arows, const u16* __restrict__ Bp,
                                        const float* __restrict__ bias, int NB, int CBn,
                                        int KS, f32x4* acc){
  const int lane = threadIdx.x & 63;
  for (int cb = 0; cb < CBn; ++cb){
    int col = cb*16 + (lane & 15);
    float b = (col < NB) ? bias[col] : 0.f;
    acc[cb] = (f32x4){b, b, b, b};
  }
  const int arow = lane & 15;
  const char* abase = (const char*)Arows + arow * 256;
  const int kb = (lane >> 4) * 16;
  const int swz = (arow & 7) << 4;
  const bfv8* __restrict__ bq = (const bfv8*)Bp + lane;
  for (int ks = 0; ks < KS; ++ks){
    bfv8 a = *(const bfv8*)(abase + ((ks*64 + kb) ^ swz));
    for (int cb = 0; cb < CBn; ++cb)
      acc[cb] = __builtin_amdgcn_mfma_f32_16x16x32_bf16(a, bq[(ks*CBn + cb) * 64], acc[cb], 0, 0, 0);
  }
}

__global__ __launch_bounds__(256, 4) void node_kernel(
    float* __restrict__ coords, float* __restrict__ hf, u16* __restrict__ hbf,
    const float* __restrict__ agg, const float* __restrict__ acc_ct, const int* __restrict__ row_start,
    const float* __restrict__ nodes,
    const u16* __restrict__ vw1p, const u16* __restrict__ vw2p,
    const u16* __restrict__ nw1p, const u16* __restrict__ nw2p,
    const float* __restrict__ vb1, const float* __restrict__ vb2,
    const float* __restrict__ nb1, const float* __restrict__ nb2){
  __shared__ __align__(16) u16 sV[4][2048];
  __shared__ float s_vt[64];

  const int tid = threadIdx.x, wid = tid >> 6, lane = tid & 63;
  const int R = wid * 16;
  const int g0 = blockIdx.x * 64;

  const int myrow = R + (lane & 15);
  const int gnode = g0 + myrow;
  const int arow = (gnode < NN) ? gnode : (NN - 1);
  const int g = lane >> 4;
  const u16*  hb = hbf + (size_t)arow * HH + g*8;
  const float* ab = agg + (size_t)arow * HH + g*8;

  f32x4 acc[8];
  // ---- vw1: h @ vw1 + vb1 (K=128, A direct from hbf) ----
  {
    const bfv8* __restrict__ bq = (const bfv8*)vw1p + lane;
    #pragma unroll
    for (int cb = 0; cb < 8; ++cb){
      float b = vb1[cb*16 + (lane & 15)];
      acc[cb] = (f32x4){b, b, b, b};
    }
    #pragma unroll
    for (int ks = 0; ks < 4; ++ks){
      bfv8 a = *(const bfv8*)(hb + ks*32);
      #pragma unroll
      for (int cb = 0; cb < 8; ++cb)
        acc[cb] = __builtin_amdgcn_mfma_f32_16x16x32_bf16(a, bq[(ks*8 + cb)*64], acc[cb], 0, 0, 0);
    }
  }
  {
    #pragma unroll
    for (int cb = 0; cb < 8; ++cb){
      #pragma unroll
      for (int j = 0; j < 4; ++j){
        int row = ((lane >> 4) << 2) + j;
        int col = cb*16 + (lane & 15);
        *(u16*)((char*)sV[wid] + row*256 + ((col*2) ^ ((row & 7) << 4))) = f2bf(fsilu(acc[cb][j]));
      }
    }
  }
  f32x4 a1[1];
  mm_lds1(sV[wid], vw2p, vb2, 1, 1, 4, a1);        // @ vw2 -> scalar
  if ((lane & 15) == 0){
    #pragma unroll
    for (int j = 0; j < 4; ++j) s_vt[R + ((lane >> 4) << 2) + j] = a1[0][j];
  }
  // coords update (per-wave own rows)
  if (lane < 16){
    int row = R + lane, gg = g0 + row;
    if (gg < NN){
      float cn = (float)(row_start[gg + 1] - row_start[gg]);
      if (cn < 1.f) cn = 1.f;
      float vt = s_vt[row];
      #pragma unroll
      for (int c = 0; c < 3; ++c){
        float val = coords[gg*3 + c] + acc_ct[gg*3 + c] / cn + vt * nodes[(size_t)gg*22 + 3 + c];
        coords[gg*3 + c] = val;
      }
    }
  }

  // ---- nw1: [h|agg] @ nw1 + nb1 (K=256; ks0..3 hbf, ks4..7 agg cvt) ----
  {
    const bfv8* __restrict__ bq = (const bfv8*)nw1p + lane;
    #pragma unroll
    for (int cb = 0; cb < 8; ++cb){
      float b = nb1[cb*16 + (lane & 15)];
      acc[cb] = (f32x4){b, b, b, b};
    }
    #pragma unroll
    for (int ks = 0; ks < 4; ++ks){
      bfv8 a = *(const bfv8*)(hb + ks*32);
      #pragma unroll
      for (int cb = 0; cb < 8; ++cb)
        acc[cb] = __builtin_amdgcn_mfma_f32_16x16x32_bf16(a, bq[(ks*8 + cb)*64], acc[cb], 0, 0, 0);
    }
    #pragma unroll
    for (int ks = 4; ks < 8; ++ks){
      float4 f0 = *(const float4*)(ab + (ks - 4)*32);
      float4 f1 = *(const float4*)(ab + (ks - 4)*32 + 4);
      union { bfv8 v; unsigned u[4]; } aa;
      aa.u[0] = f2bf(f0.x) | ((unsigned)f2bf(f0.y) << 16);
      aa.u[1] = f2bf(f0.z) | ((unsigned)f2bf(f0.w) << 16);
      aa.u[2] = f2bf(f1.x) | ((unsigned)f2bf(f1.y) << 16);
      aa.u[3] = f2bf(f1.z) | ((unsigned)f2bf(f1.w) << 16);
      #pragma unroll
      for (int cb = 0; cb < 8; ++cb)
        acc[cb] = __builtin_amdgcn_mfma_f32_16x16x32_bf16(aa.v, bq[(ks*8 + cb)*64], acc[cb], 0, 0, 0);
    }
  }
  {
    #pragma unroll
    for (int cb = 0; cb < 8; ++cb){
      #pragma unroll
      for (int j = 0; j < 4; ++j){
        int row = ((lane >> 4) << 2) + j;
        int col = cb*16 + (lane & 15);
        *(u16*)((char*)sV[wid] + row*256 + ((col*2) ^ ((row & 7) << 4))) = f2bf(fsilu(acc[cb][j]));
      }
    }
  }
  mm_lds1(sV[wid], nw2p, nb2, 128, 8, 4, acc);     // @ nw2
  {
    #pragma unroll
    for (int cb = 0; cb < 8; ++cb){
      int col = cb*16 + (lane & 15);
      #pragma unroll
      for (int j = 0; j < 4; ++j){
        int row = R + ((lane >> 4) << 2) + j, gg = g0 + row;
        if (gg < NN){
          size_t off = (size_t)gg * HH + col;
          float h = acc[cb][j] + hf[off];
          hf[off] = h;
          hbf[off] = f2bf(h);
        }
      }
    }
  }
}

// ---------------- host ----------------
extern "C" void kernel_launch(void* const* d_in, const int* in_sizes, int n_in,
                              void* d_out, int out_size, void* d_ws, size_t ws_size,
                              hipStream_t stream){
  const float* nodes = (const float*)d_in[0];
  const int*   eidx  = (const int*)d_in[1];
  const float* ef    = (const float*)d_in[2];
  const float* emb_w = (const float*)d_in[3];
  const float* emb_b = (const float*)d_in[4];
  const float* ew1 = (const float*)d_in[5];
  const float* eb1 = (const float*)d_in[6];
  const float* ew2 = (const float*)d_in[7];
  const float* eb2 = (const float*)d_in[8];
  const float* cw1 = (const float*)d_in[9];
  const float* cb1 = (const float*)d_in[10];
  const float* cw2 = (const float*)d_in[11];
  const float* cb2 = (const float*)d_in[12];
  const float* vw1 = (const float*)d_in[13];
  const float* vb1 = (const float*)d_in[14];
  const float* vw2 = (const float*)d_in[15];
  const float* vb2 = (const float*)d_in[16];
  const float* nw1 = (const float*)d_in[17];
  const float* nb1 = (const float*)d_in[18];
  const float* nw2 = (const float*)d_in[19];
  const float* nb2 = (const float*)d_in[20];

  // workspace budget ~77 MB; clean no-op if harness gives less (diagnosable absmax fail)
  constexpr size_t WS_NEEDED = 78u * 1024u * 1024u;
  if (ws_size < WS_NEEDED) return;

  char* ws = (char*)d_ws;
  size_t off = 0;
  auto alloc = [&](size_t bytes){ void* p = ws + off; off += (bytes + 255) & ~(size_t)255; return p; };
  float* coords   = (float*)alloc((size_t)NN * 3 * 4);
  float* hf       = (float*)alloc((size_t)NN * HH * 4);
  u16*   hbf      = (u16*)  alloc((size_t)NN * HH * 2);
  float* agg      = (float*)alloc((size_t)NN * 131 * 4);   // agg[N][128] + acc_ct[N][3]
  float* acc_ct   = agg + (size_t)NN * HH;
  int*   cnt_i    = (int*)  alloc((size_t)NN * 4);
  int*   row_start= (int*)  alloc((size_t)(NN + 1) * 4);
  int*   fill     = (int*)  alloc((size_t)NN * 4);
  int2*  sd_sorted= (int2*) alloc((size_t)EE * 8);
  int*   eid_sorted=(int*)  alloc((size_t)EE * 4);

  // packed weights (bf16 fragment order), per layer
  constexpr int O_EW1 = 0;
  constexpr int O_EW2 = O_EW1 + 9*8*512;
  constexpr int O_CW1 = O_EW2 + 4*8*512;
  constexpr int O_CW2 = O_CW1 + 4*8*512;
  constexpr int O_VW1 = O_CW2 + 4*1*512;
  constexpr int O_VW2 = O_VW1 + 4*8*512;
  constexpr int O_NW1 = O_VW2 + 4*1*512;
  constexpr int O_NW2 = O_NW1 + 8*8*512;
  constexpr int LAYER_PACK = O_NW2 + 4*8*512;
  u16* packs = (u16*)alloc((size_t)LAYER_PACK * 4 * 2);

  PackArgs pa;
  for (int l = 0; l < 4; ++l){
    u16* base = packs + (size_t)l * LAYER_PACK;
    int i = l * 8;
    pa.d[i+0] = { ew1 + (size_t)l*273*128, base + O_EW1, 273, 128, 8, 9, 1 };
    pa.d[i+1] = { ew2 + (size_t)l*128*128, base + O_EW2, 128, 128, 8, 4, 0 };
    pa.d[i+2] = { cw1 + (size_t)l*128*128, base + O_CW1, 128, 128, 8, 4, 0 };
    pa.d[i+3] = { cw2 + (size_t)l*128*3,   base + O_CW2, 128,   3, 1, 4, 0 };
    pa.d[i+4] = { vw1 + (size_t)l*128*128, base + O_VW1, 128, 128, 8, 4, 0 };
    pa.d[i+5] = { vw2 + (size_t)l*128*1,   base + O_VW2, 128,   1, 1, 4, 0 };
    pa.d[i+6] = { nw1 + (size_t)l*256*128, base + O_NW1, 256, 128, 8, 8, 0 };
    pa.d[i+7] = { nw2 + (size_t)l*128*128, base + O_NW2, 128, 128, 8, 4, 0 };
  }

  pack_kernel<<<32, 256, 0, stream>>>(pa);
  embed_kernel<<<(NN*4 + 255)/256, 256, 0, stream>>>(nodes, emb_w, emb_b, hf, hbf, coords);
  hipMemsetAsync(cnt_i, 0, (size_t)NN * 4, stream);
  count_kernel<<<(EE + 255)/256, 256, 0, stream>>>(eidx, cnt_i);
  scan_kernel<<<1, 256, 0, stream>>>(cnt_i, row_start, fill);
  scatter_kernel<<<(EE + 255)/256, 256, 0, stream>>>(eidx, eidx + EE, fill, sd_sorted, eid_sorted);

  for (int l = 0; l < 4; ++l){
    hipMemsetAsync(agg, 0, (size_t)NN * 131 * 4, stream);
    u16* base = packs + (size_t)l * LAYER_PACK;
    edge_kernel<<<EE/128, 512, 0, stream>>>(coords, hbf, ef, sd_sorted, eid_sorted,
        base + O_EW1, base + O_EW2, base + O_CW1, base + O_CW2,
        eb1 + l*128, eb2 + l*128, cb1 + l*128, cb2 + l*3, agg, acc_ct);
    node_kernel<<<(NN + 63)/64, 256, 0, stream>>>(coords, hf, hbf, agg, acc_ct, row_start, nodes,
        base + O_VW1, base + O_VW2, base + O_NW1, base + O_NW2,
        vb1 + l*128, vb2 + l, nb1 + l*128, nb2 + l*128);
  }

  hipMemcpyAsync(d_out, coords, (size_t)NN * 3 * 4, hipMemcpyDeviceToDevice, stream);
}

// Round 13
// 2058.446 us; speedup vs baseline: 1.1676x; 1.1676x over previous
//
#include <hip/hip_runtime.h>

constexpr int NN = 50000;
constexpr int EE = 800000;
constexpr int HH = 128;

typedef __attribute__((ext_vector_type(8))) __bf16 bfv8;
typedef __attribute__((ext_vector_type(4))) float f32x4;
typedef __attribute__((ext_vector_type(16))) float f32x16;
typedef unsigned short u16;

__device__ __forceinline__ u16 f2bf(float x){
  unsigned u = __builtin_bit_cast(unsigned, x);
  u = u + 0x7fffu + ((u >> 16) & 1u);
  return (u16)(u >> 16);
}
__device__ __forceinline__ float fsilu(float x){
  return x * __builtin_amdgcn_rcpf(1.f + __expf(-x));
}

// ---------------- 32x32x16 helpers (edge kernel) ----------------
// scratch: 32 rows x 288B (288 = 72 dwords == 8 mod 32 banks -> rows spread);
// element col c stored at byte (c*2) ^ ((row&15)<<4), data 256B < 288B row.
constexpr int SRB = 288;

// A-read + GEMM: A from wave scratch, B packed-32 global.
// B pack unit (ks*CBn+cb): lane reads 8 bf16 at unit*512 + lane*8
// (col = lane&31, k = ks*16 + (lane>>5)*8 + j).
template<int KS, int CBn>
__device__ __forceinline__ void mmW32(const u16* sB, const u16* __restrict__ Bp,
                                      const float* __restrict__ bias, int NB, f32x16* acc){
  const int lane = threadIdx.x & 63;
  const int col0 = lane & 31;
  #pragma unroll
  for (int cb = 0; cb < CBn; ++cb){
    int col = cb*32 + col0;
    float b = (col < NB) ? bias[col] : 0.f;
    #pragma unroll
    for (int r = 0; r < 16; ++r) acc[cb][r] = b;
  }
  const int row = lane & 31;
  const char* abase = (const char*)sB + row * SRB;
  const int kb = (lane >> 5) * 16;                 // byte offset of lane's 8 k
  const int swz = (row & 15) << 4;
  const bfv8* __restrict__ bq = (const bfv8*)Bp + lane;
  #pragma unroll
  for (int ks = 0; ks < KS; ++ks){
    bfv8 a = *(const bfv8*)(abase + ((ks*32 + kb) ^ swz));
    #pragma unroll
    for (int cb = 0; cb < CBn; ++cb)
      acc[cb] = __builtin_amdgcn_mfma_f32_32x32x16_bf16(a, bq[(ks*CBn + cb) * 64], acc[cb], 0, 0, 0);
  }
}

// silu(acc) -> bf16 scratch. C layout: col=lane&31, row=(r&3)+8*(r>>2)+4*(lane>>5).
template<int CBn>
__device__ __forceinline__ void silu_store32(const f32x16* acc, u16* sB){
  const int lane = threadIdx.x & 63;
  const int col0 = lane & 31;
  const int rbase = (lane >> 5) * 4;
  #pragma unroll
  for (int cb = 0; cb < CBn; ++cb){
    int col = cb*32 + col0;
    #pragma unroll
    for (int r = 0; r < 16; ++r){
      int row = (r & 3) + 8*(r >> 2) + rbase;
      *(u16*)((char*)sB + row*SRB + ((col*2) ^ ((row & 15) << 4))) = f2bf(fsilu(acc[cb][r]));
    }
  }
}

// ---------------- weight packing ----------------
// frag32==0: 16x16x32 order (unit 512 elems; k=ks*32+(lane>>4)*8+j, col=cb*16+(lane&15))
// frag32==1: 32x32x16 order (unit 512 elems; k=ks*16+(lane>>5)*8+j, col=cb*32+(lane&31))
// remap==1 (ew1): packed k order [h(256)|ef(16)|nrm|pad(15)]; source rows [h|nrm@256|ef@257..272].
struct PackDesc { const float* src; u16* dst; int K; int Nc; int CB; int ksteps; int remap; int frag32; };
struct PackArgs { PackDesc d[32]; };

__global__ __launch_bounds__(256) void pack_kernel(PackArgs pa){
  PackDesc d = pa.d[blockIdx.x];
  int total = d.ksteps * d.CB * 512;
  for (int p = threadIdx.x; p < total; p += 256){
    int j = p & 7, lane = (p >> 3) & 63, unit = p >> 9;
    int cb = unit % d.CB, ks = unit / d.CB;
    int k, col;
    if (d.frag32){
      k = ks*16 + ((lane >> 5) * 8) + j;
      col = cb*32 + (lane & 31);
    } else {
      k = ks*32 + ((lane >> 4) * 8) + j;
      col = cb*16 + (lane & 15);
    }
    int kk = k;
    if (d.remap && k >= 256) kk = (k < 272) ? (k + 1) : ((k == 272) ? 256 : 0x7fffffff);
    float v = (kk < d.K && col < d.Nc) ? d.src[(size_t)kk * d.Nc + col] : 0.f;
    d.dst[p] = f2bf(v);
  }
}

// ---------------- embedding + coords init ----------------
__global__ __launch_bounds__(256) void embed_kernel(const float* __restrict__ nodes,
    const float* __restrict__ emb_w, const float* __restrict__ emb_b,
    float* __restrict__ hf, u16* __restrict__ hbf, float* __restrict__ coords){
  int t = blockIdx.x * 256 + threadIdx.x;
  int g = t >> 2, q = t & 3;
  if (g >= NN) return;
  const float* x = nodes + (size_t)g * 22;
  float acc[32];
  #pragma unroll
  for (int c = 0; c < 32; ++c) acc[c] = emb_b[q*32 + c];
  for (int k = 0; k < 16; ++k){
    float f = x[6 + k];
    const float* wr = emb_w + k*128 + q*32;
    #pragma unroll
    for (int c = 0; c < 32; ++c) acc[c] += f * wr[c];
  }
  size_t off = (size_t)g * HH + q*32;
  #pragma unroll
  for (int c = 0; c < 32; ++c){ hf[off + c] = acc[c]; hbf[off + c] = f2bf(acc[c]); }
  if (q == 0){
    coords[g*3+0] = x[0]; coords[g*3+1] = x[1]; coords[g*3+2] = x[2];
  }
}

// ---------------- CSR build (once per launch) ----------------
__global__ __launch_bounds__(256) void count_kernel(const int* __restrict__ esrc, int* __restrict__ cnt_i){
  int e = blockIdx.x * 256 + threadIdx.x;
  if (e < EE) atomicAdd(&cnt_i[esrc[e]], 1);
}

__global__ __launch_bounds__(256) void scan_kernel(const int* __restrict__ cnt_i,
    int* __restrict__ row_start, int* __restrict__ fill){
  __shared__ int part[256];
  int t = threadIdx.x;
  int lo = t * 196, hi = lo + 196;
  if (lo > NN) lo = NN;
  if (hi > NN) hi = NN;
  int s = 0;
  for (int i = lo; i < hi; ++i) s += cnt_i[i];
  part[t] = s; __syncthreads();
  for (int d = 1; d < 256; d <<= 1){
    int v = (t >= d) ? part[t-d] : 0;
    __syncthreads();
    part[t] += v;
    __syncthreads();
  }
  int run = part[t] - s;             // exclusive prefix
  for (int i = lo; i < hi; ++i){ row_start[i] = run; fill[i] = run; run += cnt_i[i]; }
  if (t == 255) row_start[NN] = run;
}

__global__ __launch_bounds__(256) void scatter_kernel(const int* __restrict__ esrc,
    const int* __restrict__ edst, int* __restrict__ fill,
    int2* __restrict__ sd_sorted, int* __restrict__ eid_sorted){
  int e = blockIdx.x * 256 + threadIdx.x;
  if (e < EE){
    int s = esrc[e];
    int pos = atomicAdd(&fill[s], 1);
    sd_sorted[pos] = make_int2(s, edst[e]);
    eid_sorted[pos] = e;
  }
}

// ---------------- edge kernel (32x32x16 MFMA) ----------------
// 128 sorted edges/block, 4 waves x 32 rows, barrier-free after Phase A.
// One 32x32 MFMA feeds 32 output rows per B fragment -> per-edge B-load
// instruction count HALVED vs the 16x16 path (the R4..R12 invariant cost).
// A direct from global hbf; ~9KB scratch/wave (rows 288B, bank-spread).
__global__ __launch_bounds__(256) void edge_kernel(
    const float* __restrict__ coords, const u16* __restrict__ hbf, const float* __restrict__ ef,
    const int2* __restrict__ sd_sorted, const int* __restrict__ eid_sorted,
    const u16* __restrict__ ew1p, const u16* __restrict__ ew2p,
    const u16* __restrict__ cw1p, const u16* __restrict__ cw2p,
    const float* __restrict__ eb1, const float* __restrict__ eb2,
    const float* __restrict__ cb1, const float* __restrict__ cb2,
    float* __restrict__ agg, float* __restrict__ acc_ct){
  __shared__ __align__(16) u16 sBuf[4][32 * SRB / 2];   // 9216B per wave
  __shared__ float4 s_cdn[128];
  __shared__ int s_src[132];
  __shared__ int s_eid[128];

  const int tid = threadIdx.x, wid = tid >> 6, lane = tid & 63;
  const int R = wid * 32;
  const int e0 = blockIdx.x * 128;

  // Phase A: per-edge scalars (wave-own rows; same-wave in-order DS)
  if (lane < 32){
    int row = R + lane;
    int e = e0 + row;
    int2 sd = sd_sorted[e];
    float cx = coords[sd.x*3+0] - coords[sd.y*3+0];
    float cy = coords[sd.x*3+1] - coords[sd.y*3+1];
    float cz = coords[sd.x*3+2] - coords[sd.y*3+2];
    float nrm = sqrtf(cx*cx + cy*cy + cz*cz);
    s_cdn[row] = make_float4(cx, cy, cz, nrm);
    s_src[row] = sd.x; s_eid[row] = eid_sorted[e];
  }
  if (tid == 0) s_src[128] = -1;   // sentinel for grow+1 read at block edge

  const int myrow = R + (lane & 31);
  const int kh = lane >> 5;                         // k half (0/1)
  int2 sd = sd_sorted[e0 + myrow];                  // L1-hot re-read
  const u16* hsb = hbf + (size_t)sd.x * HH + kh*8;
  const u16* hdb = hbf + (size_t)sd.y * HH + kh*8;
  u16* sB = sBuf[wid];
  const int col0 = lane & 31;
  const int rbase4 = (lane >> 5) * 4;

  f32x16 acc[4];
  // ---- ew1: x @ ew1 + eb1 (A direct from global; K = 18 ksteps of 16) ----
  {
    const bfv8* __restrict__ bq = (const bfv8*)ew1p + lane;
    #pragma unroll
    for (int cb = 0; cb < 4; ++cb){
      float b = eb1[cb*32 + col0];
      #pragma unroll
      for (int r = 0; r < 16; ++r) acc[cb][r] = b;
    }
    #pragma unroll
    for (int ks = 0; ks < 8; ++ks){                 // k 0..127 = h_s
      bfv8 a = *(const bfv8*)(hsb + ks*16);
      #pragma unroll
      for (int cb = 0; cb < 4; ++cb)
        acc[cb] = __builtin_amdgcn_mfma_f32_32x32x16_bf16(a, bq[(ks*4 + cb)*64], acc[cb], 0, 0, 0);
    }
    #pragma unroll
    for (int ks = 8; ks < 16; ++ks){                // k 128..255 = h_d
      bfv8 a = *(const bfv8*)(hdb + (ks - 8)*16);
      #pragma unroll
      for (int cb = 0; cb < 4; ++cb)
        acc[cb] = __builtin_amdgcn_mfma_f32_32x32x16_bf16(a, bq[(ks*4 + cb)*64], acc[cb], 0, 0, 0);
    }
    // ks16: k 256..271 = ef[0..15]; ks17: k 272..287 = [nrm | zeros]
    const int my_eid = s_eid[myrow];
    union { bfv8 v; u16 s[8]; unsigned u[4]; } a16, a17;
    {
      float4 f0 = *(const float4*)(ef + (size_t)my_eid * 16 + kh*8);
      float4 f1 = *(const float4*)(ef + (size_t)my_eid * 16 + kh*8 + 4);
      a16.u[0] = f2bf(f0.x) | ((unsigned)f2bf(f0.y) << 16);
      a16.u[1] = f2bf(f0.z) | ((unsigned)f2bf(f0.w) << 16);
      a16.u[2] = f2bf(f1.x) | ((unsigned)f2bf(f1.y) << 16);
      a16.u[3] = f2bf(f1.z) | ((unsigned)f2bf(f1.w) << 16);
    }
    a17.u[0] = a17.u[1] = a17.u[2] = a17.u[3] = 0u;
    if (kh == 0) a17.s[0] = f2bf(s_cdn[myrow].w);
    #pragma unroll
    for (int cb = 0; cb < 4; ++cb){
      acc[cb] = __builtin_amdgcn_mfma_f32_32x32x16_bf16(a16.v, bq[(16*4 + cb)*64], acc[cb], 0, 0, 0);
      acc[cb] = __builtin_amdgcn_mfma_f32_32x32x16_bf16(a17.v, bq[(17*4 + cb)*64], acc[cb], 0, 0, 0);
    }
  }
  silu_store32<4>(acc, sB);                         // w(B), wave-private

  mmW32<8, 4>(sB, ew2p, eb2, 128, acc);             // r(B): silu(.) @ ew2 + eb2
  // m: silu, segmented-reduce (rows in 4 consecutive-row groups), flush
  // atomics; bf16 back into sB for cw1.
  {
    #pragma unroll
    for (int cb = 0; cb < 4; ++cb){
      int col = cb*32 + col0;
      #pragma unroll
      for (int grp = 0; grp < 4; ++grp){
        float run = 0.f;
        #pragma unroll
        for (int j = 0; j < 4; ++j){
          int r = grp*4 + j;                        // reg index
          int row = grp*8 + rbase4 + j;             // (r&3)+8*(r>>2)+4*kh
          int grow = R + row;
          float m = fsilu(acc[cb][r]);
          run += m;
          *(u16*)((char*)sB + row*SRB + ((col*2) ^ ((row & 15) << 4))) = f2bf(m);
          int src = s_src[grow];
          if (j == 3 || s_src[grow + 1] != src){
            atomicAdd(&agg[(size_t)src * HH + col], run);
            run = 0.f;
          }
        }
      }
    }
  }

  mmW32<8, 4>(sB, cw1p, cb1, 128, acc);             // r(B): m @ cw1 + cb1
  silu_store32<4>(acc, sB);                         // w(B)

  f32x16 a4[1];
  mmW32<8, 1>(sB, cw2p, cb2, 3, a4);                // r(B): silu(.) @ cw2 + cb2
  {
    if (col0 < 3){
      #pragma unroll
      for (int grp = 0; grp < 4; ++grp){
        float run = 0.f;
        #pragma unroll
        for (int j = 0; j < 4; ++j){
          int r = grp*4 + j;
          int row = grp*8 + rbase4 + j;
          int grow = R + row;
          float4 cdn = s_cdn[grow];
          float cdv = (col0 == 0) ? cdn.x : ((col0 == 1) ? cdn.y : cdn.z);
          run += cdv * a4[0][r];
          int src = s_src[grow];
          if (j == 3 || s_src[grow + 1] != src){
            atomicAdd(&acc_ct[(size_t)src * 3 + col0], run);
            run = 0.f;
          }
        }
      }
    }
  }
}

// ---------------- node kernel (16x16 path, unchanged) ----------------
__device__ __forceinline__ void mm_lds1(const u16* Arows, const u16* __restrict__ Bp,
                                        const float* __restrict__ bias, int NB, int CBn,
                                        int KS, f32x4* acc){
  const int lane = threadIdx.x & 63;
  for (int cb = 0; cb < CBn; ++cb){
    int col = cb*16 + (lane & 15);
    float b = (col < NB) ? bias[col] : 0.f;
    acc[cb] = (f32x4){b, b, b, b};
  }
  const int arow = lane & 15;
  const char* abase = (const char*)Arows + arow * 256;
  const int kb = (lane >> 4) * 16;
  const int swz = (arow & 7) << 4;
  const bfv8* __restrict__ bq = (const bfv8*)Bp + lane;
  for (int ks = 0; ks < KS; ++ks){
    bfv8 a = *(const bfv8*)(abase + ((ks*64 + kb) ^ swz));
    for (int cb = 0; cb < CBn; ++cb)
      acc[cb] = __builtin_amdgcn_mfma_f32_16x16x32_bf16(a, bq[(ks*CBn + cb) * 64], acc[cb], 0, 0, 0);
  }
}

__global__ __launch_bounds__(256, 4) void node_kernel(
    float* __restrict__ coords, float* __restrict__ hf, u16* __restrict__ hbf,
    const float* __restrict__ agg, const float* __restrict__ acc_ct, const int* __restrict__ row_start,
    const float* __restrict__ nodes,
    const u16* __restrict__ vw1p, const u16* __restrict__ vw2p,
    const u16* __restrict__ nw1p, const u16* __restrict__ nw2p,
    const float* __restrict__ vb1, const float* __restrict__ vb2,
    const float* __restrict__ nb1, const float* __restrict__ nb2){
  __shared__ __align__(16) u16 sV[4][2048];
  __shared__ float s_vt[64];

  const int tid = threadIdx.x, wid = tid >> 6, lane = tid & 63;
  const int R = wid * 16;
  const int g0 = blockIdx.x * 64;

  const int myrow = R + (lane & 15);
  const int gnode = g0 + myrow;
  const int arow = (gnode < NN) ? gnode : (NN - 1);
  const int g = lane >> 4;
  const u16*  hb = hbf + (size_t)arow * HH + g*8;
  const float* ab = agg + (size_t)arow * HH + g*8;

  f32x4 acc[8];
  // ---- vw1: h @ vw1 + vb1 (K=128, A direct from hbf) ----
  {
    const bfv8* __restrict__ bq = (const bfv8*)vw1p + lane;
    #pragma unroll
    for (int cb = 0; cb < 8; ++cb){
      float b = vb1[cb*16 + (lane & 15)];
      acc[cb] = (f32x4){b, b, b, b};
    }
    #pragma unroll
    for (int ks = 0; ks < 4; ++ks){
      bfv8 a = *(const bfv8*)(hb + ks*32);
      #pragma unroll
      for (int cb = 0; cb < 8; ++cb)
        acc[cb] = __builtin_amdgcn_mfma_f32_16x16x32_bf16(a, bq[(ks*8 + cb)*64], acc[cb], 0, 0, 0);
    }
  }
  {
    #pragma unroll
    for (int cb = 0; cb < 8; ++cb){
      #pragma unroll
      for (int j = 0; j < 4; ++j){
        int row = ((lane >> 4) << 2) + j;
        int col = cb*16 + (lane & 15);
        *(u16*)((char*)sV[wid] + row*256 + ((col*2) ^ ((row & 7) << 4))) = f2bf(fsilu(acc[cb][j]));
      }
    }
  }
  f32x4 a1[1];
  mm_lds1(sV[wid], vw2p, vb2, 1, 1, 4, a1);        // @ vw2 -> scalar
  if ((lane & 15) == 0){
    #pragma unroll
    for (int j = 0; j < 4; ++j) s_vt[R + ((lane >> 4) << 2) + j] = a1[0][j];
  }
  if (lane < 16){
    int row = R + lane, gg = g0 + row;
    if (gg < NN){
      float cn = (float)(row_start[gg + 1] - row_start[gg]);
      if (cn < 1.f) cn = 1.f;
      float vt = s_vt[row];
      #pragma unroll
      for (int c = 0; c < 3; ++c){
        float val = coords[gg*3 + c] + acc_ct[gg*3 + c] / cn + vt * nodes[(size_t)gg*22 + 3 + c];
        coords[gg*3 + c] = val;
      }
    }
  }

  // ---- nw1: [h|agg] @ nw1 + nb1 (K=256; ks0..3 hbf, ks4..7 agg cvt) ----
  {
    const bfv8* __restrict__ bq = (const bfv8*)nw1p + lane;
    #pragma unroll
    for (int cb = 0; cb < 8; ++cb){
      float b = nb1[cb*16 + (lane & 15)];
      acc[cb] = (f32x4){b, b, b, b};
    }
    #pragma unroll
    for (int ks = 0; ks < 4; ++ks){
      bfv8 a = *(const bfv8*)(hb + ks*32);
      #pragma unroll
      for (int cb = 0; cb < 8; ++cb)
        acc[cb] = __builtin_amdgcn_mfma_f32_16x16x32_bf16(a, bq[(ks*8 + cb)*64], acc[cb], 0, 0, 0);
    }
    #pragma unroll
    for (int ks = 4; ks < 8; ++ks){
      float4 f0 = *(const float4*)(ab + (ks - 4)*32);
      float4 f1 = *(const float4*)(ab + (ks - 4)*32 + 4);
      union { bfv8 v; unsigned u[4]; } aa;
      aa.u[0] = f2bf(f0.x) | ((unsigned)f2bf(f0.y) << 16);
      aa.u[1] = f2bf(f0.z) | ((unsigned)f2bf(f0.w) << 16);
      aa.u[2] = f2bf(f1.x) | ((unsigned)f2bf(f1.y) << 16);
      aa.u[3] = f2bf(f1.z) | ((unsigned)f2bf(f1.w) << 16);
      #pragma unroll
      for (int cb = 0; cb < 8; ++cb)
        acc[cb] = __builtin_amdgcn_mfma_f32_16x16x32_bf16(aa.v, bq[(ks*8 + cb)*64], acc[cb], 0, 0, 0);
    }
  }
  {
    #pragma unroll
    for (int cb = 0; cb < 8; ++cb){
      #pragma unroll
      for (int j = 0; j < 4; ++j){
        int row = ((lane >> 4) << 2) + j;
        int col = cb*16 + (lane & 15);
        *(u16*)((char*)sV[wid] + row*256 + ((col*2) ^ ((row & 7) << 4))) = f2bf(fsilu(acc[cb][j]));
      }
    }
  }
  mm_lds1(sV[wid], nw2p, nb2, 128, 8, 4, acc);     // @ nw2
  {
    #pragma unroll
    for (int cb = 0; cb < 8; ++cb){
      int col = cb*16 + (lane & 15);
      #pragma unroll
      for (int j = 0; j < 4; ++j){
        int row = R + ((lane >> 4) << 2) + j, gg = g0 + row;
        if (gg < NN){
          size_t off = (size_t)gg * HH + col;
          float h = acc[cb][j] + hf[off];
          hf[off] = h;
          hbf[off] = f2bf(h);
        }
      }
    }
  }
}

// ---------------- host ----------------
extern "C" void kernel_launch(void* const* d_in, const int* in_sizes, int n_in,
                              void* d_out, int out_size, void* d_ws, size_t ws_size,
                              hipStream_t stream){
  const float* nodes = (const float*)d_in[0];
  const int*   eidx  = (const int*)d_in[1];
  const float* ef    = (const float*)d_in[2];
  const float* emb_w = (const float*)d_in[3];
  const float* emb_b = (const float*)d_in[4];
  const float* ew1 = (const float*)d_in[5];
  const float* eb1 = (const float*)d_in[6];
  const float* ew2 = (const float*)d_in[7];
  const float* eb2 = (const float*)d_in[8];
  const float* cw1 = (const float*)d_in[9];
  const float* cb1 = (const float*)d_in[10];
  const float* cw2 = (const float*)d_in[11];
  const float* cb2 = (const float*)d_in[12];
  const float* vw1 = (const float*)d_in[13];
  const float* vb1 = (const float*)d_in[14];
  const float* vw2 = (const float*)d_in[15];
  const float* vb2 = (const float*)d_in[16];
  const float* nw1 = (const float*)d_in[17];
  const float* nb1 = (const float*)d_in[18];
  const float* nw2 = (const float*)d_in[19];
  const float* nb2 = (const float*)d_in[20];

  constexpr size_t WS_NEEDED = 78u * 1024u * 1024u;
  if (ws_size < WS_NEEDED) return;

  char* ws = (char*)d_ws;
  size_t off = 0;
  auto alloc = [&](size_t bytes){ void* p = ws + off; off += (bytes + 255) & ~(size_t)255; return p; };
  float* coords   = (float*)alloc((size_t)NN * 3 * 4);
  float* hf       = (float*)alloc((size_t)NN * HH * 4);
  u16*   hbf      = (u16*)  alloc((size_t)NN * HH * 2);
  float* agg      = (float*)alloc((size_t)NN * 131 * 4);   // agg[N][128] + acc_ct[N][3]
  float* acc_ct   = agg + (size_t)NN * HH;
  int*   cnt_i    = (int*)  alloc((size_t)NN * 4);
  int*   row_start= (int*)  alloc((size_t)(NN + 1) * 4);
  int*   fill     = (int*)  alloc((size_t)NN * 4);
  int2*  sd_sorted= (int2*) alloc((size_t)EE * 8);
  int*   eid_sorted=(int*)  alloc((size_t)EE * 4);

  // packed weights: edge weights in 32x32 fragment order, node in 16x16.
  constexpr int O_EW1 = 0;                    // 18ks x 4cb x 512 = 36864
  constexpr int O_EW2 = O_EW1 + 18*4*512;
  constexpr int O_CW1 = O_EW2 + 8*4*512;      // +16384
  constexpr int O_CW2 = O_CW1 + 8*4*512;      // +16384
  constexpr int O_VW1 = O_CW2 + 8*1*512;      // +4096
  constexpr int O_VW2 = O_VW1 + 4*8*512;
  constexpr int O_NW1 = O_VW2 + 4*1*512;
  constexpr int O_NW2 = O_NW1 + 8*8*512;
  constexpr int LAYER_PACK = O_NW2 + 4*8*512;
  u16* packs = (u16*)alloc((size_t)LAYER_PACK * 4 * 2);

  PackArgs pa;
  for (int l = 0; l < 4; ++l){
    u16* base = packs + (size_t)l * LAYER_PACK;
    int i = l * 8;
    pa.d[i+0] = { ew1 + (size_t)l*273*128, base + O_EW1, 273, 128, 4, 18, 1, 1 };
    pa.d[i+1] = { ew2 + (size_t)l*128*128, base + O_EW2, 128, 128, 4,  8, 0, 1 };
    pa.d[i+2] = { cw1 + (size_t)l*128*128, base + O_CW1, 128, 128, 4,  8, 0, 1 };
    pa.d[i+3] = { cw2 + (size_t)l*128*3,   base + O_CW2, 128,   3, 1,  8, 0, 1 };
    pa.d[i+4] = { vw1 + (size_t)l*128*128, base + O_VW1, 128, 128, 8,  4, 0, 0 };
    pa.d[i+5] = { vw2 + (size_t)l*128*1,   base + O_VW2, 128,   1, 1,  4, 0, 0 };
    pa.d[i+6] = { nw1 + (size_t)l*256*128, base + O_NW1, 256, 128, 8,  8, 0, 0 };
    pa.d[i+7] = { nw2 + (size_t)l*128*128, base + O_NW2, 128, 128, 8,  4, 0, 0 };
  }

  pack_kernel<<<32, 256, 0, stream>>>(pa);
  embed_kernel<<<(NN*4 + 255)/256, 256, 0, stream>>>(nodes, emb_w, emb_b, hf, hbf, coords);
  hipMemsetAsync(cnt_i, 0, (size_t)NN * 4, stream);
  count_kernel<<<(EE + 255)/256, 256, 0, stream>>>(eidx, cnt_i);
  scan_kernel<<<1, 256, 0, stream>>>(cnt_i, row_start, fill);
  scatter_kernel<<<(EE + 255)/256, 256, 0, stream>>>(eidx, eidx + EE, fill, sd_sorted, eid_sorted);

  for (int l = 0; l < 4; ++l){
    hipMemsetAsync(agg, 0, (size_t)NN * 131 * 4, stream);
    u16* base = packs + (size_t)l * LAYER_PACK;
    edge_kernel<<<EE/128, 256, 0, stream>>>(coords, hbf, ef, sd_sorted, eid_sorted,
        base + O_EW1, base + O_EW2, base + O_CW1, base + O_CW2,
        eb1 + l*128, eb2 + l*128, cb1 + l*128, cb2 + l*3, agg, acc_ct);
    node_kernel<<<(NN + 63)/64, 256, 0, stream>>>(coords, hf, hbf, agg, acc_ct, row_start, nodes,
        base + O_VW1, base + O_VW2, base + O_NW1, base + O_NW2,
        vb1 + l*128, vb2 + l, nb1 + l*128, nb2 + l*128);
  }

  hipMemcpyAsync(d_out, coords, (size_t)NN * 3 * 4, hipMemcpyDeviceToDevice, stream);
}